// Round 4
// baseline (384.023 us; speedup 1.0000x reference)
//
#include <hip/hip_runtime.h>

#define KEPS  1e-16f
#define LOG2E 1.44269504088896340736f

// ---- d_ws float layout (2178 floats = 8712 B) ----
// [0..99]      tsc  : tail scale  = 1/(nmax-nmin+eps)            [c][f]
// [100..199]   tbi  : tail bias   = -nmin*tsc                    [c][f]
// [200..999]   tew  : tail_enc_w * -log2e                        [c][i][f]
// [1000..1079] teb  : tail_enc_b * -log2e                        [c][i]
// [1080..1879] tdw  : tail_dec_w * -log2e                        [c][f][i]
// [1880..1979] tdb  : tail_dec_b * -log2e                        [c][f]
// [1980..1989] hsc  : head scale                                 [c]
// [1990..1999] hbi  : head bias (-nmin*hsc)                      [c]
// [2000..2079] hew  : head_enc_w * -log2e                        [i][c]
// [2080..2087] heb  : head_enc_b * -log2e                        [i]
// [2088..2167] hdw  : head_dec_w * -log2e                        [c][i]
// [2168..2177] hdb  : head_dec_b * -log2e                        [c]

__global__ void kitsune_prep(
    const float* __restrict__ tew, const float* __restrict__ teb,
    const float* __restrict__ tdw, const float* __restrict__ tdb,
    const float* __restrict__ tnmin, const float* __restrict__ tnmax,
    const float* __restrict__ hew, const float* __restrict__ heb,
    const float* __restrict__ hdw, const float* __restrict__ hdb,
    const float* __restrict__ hnmin, const float* __restrict__ hnmax,
    float* __restrict__ ws)
{
    const int i = threadIdx.x;  // one block of 256
    for (int k = i; k < 100; k += 256) {
        float s = 1.0f / (tnmax[k] - tnmin[k] + KEPS);
        ws[k]       = s;
        ws[100 + k] = -tnmin[k] * s;
        ws[1880 + k] = tdb[k] * -LOG2E;
    }
    for (int k = i; k < 800; k += 256) {
        ws[200 + k]  = tew[k] * -LOG2E;
        ws[1080 + k] = tdw[k] * -LOG2E;
    }
    for (int k = i; k < 80; k += 256) {
        ws[1000 + k] = teb[k] * -LOG2E;
        ws[2000 + k] = hew[k] * -LOG2E;
        ws[2088 + k] = hdw[k] * -LOG2E;
    }
    if (i < 10) {
        float s = 1.0f / (hnmax[i] - hnmin[i] + KEPS);
        ws[1980 + i] = s;
        ws[1990 + i] = -hnmin[i] * s;
        ws[2168 + i] = hdb[i] * -LOG2E;
    }
    if (i < 8) ws[2080 + i] = heb[i] * -LOG2E;
}

// sigmoid with the -log2e already folded into the preceding matmul:
// sig2(a) = 1/(1+2^a) where a = -log2e*(w.x+b)
__device__ __forceinline__ float sig2(float a) {
    return __builtin_amdgcn_rcpf(1.0f + __builtin_amdgcn_exp2f(a));
}

__global__ __launch_bounds__(256, 4) void kitsune_main(
    const float* __restrict__ x,    // [B][100]
    const float* __restrict__ ws,   // prepped params (wave-uniform -> s_load)
    float* __restrict__ out_xhat,   // [B][10]
    float* __restrict__ out_t,      // [B][10]
    int B, int half)
{
    const int tid = blockIdx.x * 256 + threadIdx.x;
    const int b0 = tid;
    const int b1 = tid + half;
    const bool vA = (b0 < half);
    const bool vB = (b1 < B);

    // ---- load both rows; all indices compile-time (registers, no scratch).
    float xA[100], xB[100];
    if (vA) {
        const float4* g = reinterpret_cast<const float4*>(x + (size_t)b0 * 100);
        #pragma unroll
        for (int q = 0; q < 25; ++q) {
            float4 v = g[q];
            xA[4*q] = v.x; xA[4*q+1] = v.y; xA[4*q+2] = v.z; xA[4*q+3] = v.w;
        }
    }
    if (vB) {
        const float4* g = reinterpret_cast<const float4*>(x + (size_t)b1 * 100);
        #pragma unroll
        for (int q = 0; q < 25; ++q) {
            float4 v = g[q];
            xB[4*q] = v.x; xB[4*q+1] = v.y; xB[4*q+2] = v.z; xB[4*q+3] = v.w;
        }
    }

    float tailsA[10], tailsB[10];

    #pragma unroll
    for (int c = 0; c < 10; ++c) {
        // normalise: xn = fma(x, scale, bias)   (1 FMA, no rcp)
        float xnA[10], xnB[10];
        #pragma unroll
        for (int f = 0; f < 10; ++f) {
            float s  = ws[c*10 + f];
            float bi = ws[100 + c*10 + f];
            xnA[f] = fmaf(xA[c*10 + f], s, bi);
            xnB[f] = fmaf(xB[c*10 + f], s, bi);
        }
        // encoder (weights pre-scaled by -log2e)
        float hA[8], hB[8];
        #pragma unroll
        for (int i = 0; i < 8; ++i) {
            float a0 = ws[1000 + c*8 + i];
            float aA = a0, aB = a0;
            #pragma unroll
            for (int f = 0; f < 10; ++f) {
                float w = ws[200 + (c*8 + i)*10 + f];
                aA = fmaf(w, xnA[f], aA);
                aB = fmaf(w, xnB[f], aB);
            }
            hA[i] = sig2(aA);
            hB[i] = sig2(aB);
        }
        // decoder + RMSE
        float ssA = 0.0f, ssB = 0.0f;
        #pragma unroll
        for (int f = 0; f < 10; ++f) {
            float a0 = ws[1880 + c*10 + f];
            float aA = a0, aB = a0;
            #pragma unroll
            for (int i = 0; i < 8; ++i) {
                float w = ws[1080 + (c*10 + f)*8 + i];
                aA = fmaf(w, hA[i], aA);
                aB = fmaf(w, hB[i], aB);
            }
            float dA = sig2(aA) - xnA[f]; ssA = fmaf(dA, dA, ssA);
            float dB = sig2(aB) - xnB[f]; ssB = fmaf(dB, dB, ssB);
        }
        float lA = __fsqrt_rn(ssA * 0.1f);
        float lB = __fsqrt_rn(ssB * 0.1f);
        tailsA[c] = (lA == 0.0f) ? 0.01f : lA;
        tailsB[c] = (lB == 0.0f) ? 0.01f : lB;
    }

    // ---- head (t is a true output: no exp-folding in the normalise) ----
    float tA[10], tB[10];
    #pragma unroll
    for (int c = 0; c < 10; ++c) {
        float s = ws[1980 + c], bi = ws[1990 + c];
        tA[c] = fmaf(tailsA[c], s, bi);
        tB[c] = fmaf(tailsB[c], s, bi);
    }
    float hhA[8], hhB[8];
    #pragma unroll
    for (int i = 0; i < 8; ++i) {
        float a0 = ws[2080 + i];
        float aA = a0, aB = a0;
        #pragma unroll
        for (int c = 0; c < 10; ++c) {
            float w = ws[2000 + i*10 + c];
            aA = fmaf(w, tA[c], aA);
            aB = fmaf(w, tB[c], aB);
        }
        hhA[i] = sig2(aA);
        hhB[i] = sig2(aB);
    }
    float xhA[10], xhB[10];
    #pragma unroll
    for (int c = 0; c < 10; ++c) {
        float a0 = ws[2168 + c];
        float aA = a0, aB = a0;
        #pragma unroll
        for (int i = 0; i < 8; ++i) {
            float w = ws[2088 + c*8 + i];
            aA = fmaf(w, hhA[i], aA);
            aB = fmaf(w, hhB[i], aB);
        }
        xhA[c] = sig2(aA);
        xhB[c] = sig2(aB);
    }

    // ---- stores (40B rows -> float2) ----
    if (vA) {
        float* po = out_xhat + (size_t)b0 * 10;
        float* pt = out_t    + (size_t)b0 * 10;
        #pragma unroll
        for (int j = 0; j < 5; ++j) {
            *reinterpret_cast<float2*>(po + 2*j) = make_float2(xhA[2*j], xhA[2*j+1]);
            *reinterpret_cast<float2*>(pt + 2*j) = make_float2(tA[2*j],  tA[2*j+1]);
        }
    }
    if (vB) {
        float* po = out_xhat + (size_t)b1 * 10;
        float* pt = out_t    + (size_t)b1 * 10;
        #pragma unroll
        for (int j = 0; j < 5; ++j) {
            *reinterpret_cast<float2*>(po + 2*j) = make_float2(xhB[2*j], xhB[2*j+1]);
            *reinterpret_cast<float2*>(pt + 2*j) = make_float2(tB[2*j],  tB[2*j+1]);
        }
    }
}

extern "C" void kernel_launch(void* const* d_in, const int* in_sizes, int n_in,
                              void* d_out, int out_size, void* d_ws, size_t ws_size,
                              hipStream_t stream) {
    const float* x          = (const float*)d_in[0];
    const float* tail_enc_w = (const float*)d_in[1];
    const float* tail_enc_b = (const float*)d_in[2];
    const float* tail_dec_w = (const float*)d_in[3];
    const float* tail_dec_b = (const float*)d_in[4];
    const float* tail_nmin  = (const float*)d_in[5];
    const float* tail_nmax  = (const float*)d_in[6];
    const float* head_enc_w = (const float*)d_in[7];
    const float* head_enc_b = (const float*)d_in[8];
    const float* head_dec_w = (const float*)d_in[9];
    const float* head_dec_b = (const float*)d_in[10];
    const float* head_nmin  = (const float*)d_in[11];
    const float* head_nmax  = (const float*)d_in[12];

    const int B = in_sizes[0] / 100;

    float* out_xhat = (float*)d_out;             // [B][10], first in tuple
    float* out_t    = out_xhat + (size_t)B * 10; // [B][10], second in tuple
    float* ws       = (float*)d_ws;              // 8712 B used

    kitsune_prep<<<1, 256, 0, stream>>>(
        tail_enc_w, tail_enc_b, tail_dec_w, tail_dec_b, tail_nmin, tail_nmax,
        head_enc_w, head_enc_b, head_dec_w, head_dec_b, head_nmin, head_nmax, ws);

    const int half = (B + 1) / 2;                // rows per pass; thread t does t and t+half
    const int grid = (half + 255) / 256;         // B=524288 -> 1024 blocks = 16 waves/CU
    kitsune_main<<<grid, 256, 0, stream>>>(x, ws, out_xhat, out_t, B, half);
}

// Round 5
// 144.173 us; speedup vs baseline: 2.6636x; 2.6636x over previous
//
#include <hip/hip_runtime.h>

#define KEPS  1e-16f
#define LOG2E 1.44269504088896340736f

// ---- d_ws float layout (2178 floats) ----
// [0..99]      tsc : 1/(nmax-nmin+eps)              [c][f]
// [100..199]   tbi : -nmin*tsc                      [c][f]
// [200..999]   tew : tail_enc_w * -log2e            [c][i][f]
// [1000..1079] teb : tail_enc_b * -log2e            [c][i]
// [1080..1879] tdw : tail_dec_w * -log2e            [c][f][i]
// [1880..1979] tdb : tail_dec_b * -log2e            [c][f]
// [1980..1989] hsc : head scale                     [c]
// [1990..1999] hbi : -hnmin*hsc                     [c]
// [2000..2079] hewT: head_enc_w^T * -log2e          [c][i]  (transposed!)
// [2080..2087] heb : head_enc_b * -log2e            [i]
// [2088..2167] hdw : head_dec_w * -log2e            [c][i]
// [2168..2177] hdb : head_dec_b * -log2e            [c]

__global__ void kitsune_prep(
    const float* __restrict__ tew, const float* __restrict__ teb,
    const float* __restrict__ tdw, const float* __restrict__ tdb,
    const float* __restrict__ tnmin, const float* __restrict__ tnmax,
    const float* __restrict__ hew, const float* __restrict__ heb,
    const float* __restrict__ hdw, const float* __restrict__ hdb,
    const float* __restrict__ hnmin, const float* __restrict__ hnmax,
    float* __restrict__ ws)
{
    const int i = threadIdx.x;  // one block of 256
    for (int k = i; k < 100; k += 256) {
        float s = 1.0f / (tnmax[k] - tnmin[k] + KEPS);
        ws[k]        = s;
        ws[100 + k]  = -tnmin[k] * s;
        ws[1880 + k] = tdb[k] * -LOG2E;
    }
    for (int k = i; k < 800; k += 256) {
        ws[200 + k]  = tew[k] * -LOG2E;
        ws[1080 + k] = tdw[k] * -LOG2E;
    }
    for (int k = i; k < 80; k += 256) {
        ws[1000 + k] = teb[k] * -LOG2E;
        int c = k >> 3, ii = k & 7;                 // hewT[c][i] = hew[i][c]
        ws[2000 + k] = hew[ii * 10 + c] * -LOG2E;
        ws[2088 + k] = hdw[k] * -LOG2E;
    }
    if (i < 10) {
        float s = 1.0f / (hnmax[i] - hnmin[i] + KEPS);
        ws[1980 + i] = s;
        ws[1990 + i] = -hnmin[i] * s;
        ws[2168 + i] = hdb[i] * -LOG2E;
    }
    if (i < 8) ws[2080 + i] = heb[i] * -LOG2E;
}

// sigmoid with -log2e pre-folded into the matmul: sig2(a) = 1/(1+2^a)
__device__ __forceinline__ float sig2(float a) {
    return __builtin_amdgcn_rcpf(1.0f + __builtin_amdgcn_exp2f(a));
}

__global__ __launch_bounds__(256) void kitsune_main(
    const float* __restrict__ x,    // [B][100]
    const float* __restrict__ ws,   // prepped params (uniform idx -> s_load)
    float* __restrict__ out_xhat,   // [B][10]
    float* __restrict__ out_t,      // [B][10]
    int B)
{
    const int tid = blockIdx.x * 256 + threadIdx.x;
    const int b0 = 2 * tid;
    if (b0 >= B) return;
    const bool vB = (b0 + 1) < B;

    const float* pA = x + (size_t)b0 * 100;
    const float* pB = vB ? pA + 100 : pA;   // degenerate but safe

    float* otA = out_t + (size_t)b0 * 10;
    float* otB = otA + 10;

    // head-encoder accumulators (compile-time indexed only)
    float hhA[8], hhB[8];
    #pragma unroll
    for (int i = 0; i < 8; ++i) { hhA[i] = 0.0f; hhB[i] = 0.0f; }

    float tHoldA = 0.0f, tHoldB = 0.0f;   // even-c t values awaiting paired store

    // ---- 10 tail AEs, cluster-streamed: only 2x10 inputs live at a time.
    // Two fully independent chains (A,B) interleaved everywhere for ILP.
    for (int c = 0; c < 10; ++c) {
        // load this cluster (8B-aligned: byte offset b*400 + c*40)
        float xA[10], xB[10];
        {
            const float2* qA = reinterpret_cast<const float2*>(pA + c * 10);
            const float2* qB = reinterpret_cast<const float2*>(pB + c * 10);
            #pragma unroll
            for (int j = 0; j < 5; ++j) {
                float2 a = qA[j], b = qB[j];
                xA[2*j] = a.x; xA[2*j+1] = a.y;
                xB[2*j] = b.x; xB[2*j+1] = b.y;
            }
        }

        // normalise: 1 FMA each (scale/bias precomputed)
        float xnA[10], xnB[10];
        #pragma unroll
        for (int f = 0; f < 10; ++f) {
            float s  = ws[c * 10 + f];
            float bi = ws[100 + c * 10 + f];
            xnA[f] = fmaf(xA[f], s, bi);
            xnB[f] = fmaf(xB[f], s, bi);
        }

        // encoder (weights pre-scaled by -log2e)
        float hA[8], hB[8];
        #pragma unroll
        for (int i = 0; i < 8; ++i) {
            float a0 = ws[1000 + c * 8 + i];
            float aA = a0, aB = a0;
            #pragma unroll
            for (int f = 0; f < 10; ++f) {
                float w = ws[200 + (c * 8 + i) * 10 + f];
                aA = fmaf(w, xnA[f], aA);
                aB = fmaf(w, xnB[f], aB);
            }
            hA[i] = sig2(aA);
            hB[i] = sig2(aB);
        }

        // decoder + RMSE (2 accumulators -> half the serial chain)
        float s0A = 0.0f, s1A = 0.0f, s0B = 0.0f, s1B = 0.0f;
        #pragma unroll
        for (int f = 0; f < 10; ++f) {
            float a0 = ws[1880 + c * 10 + f];
            float aA = a0, aB = a0;
            #pragma unroll
            for (int i = 0; i < 8; ++i) {
                float w = ws[1080 + (c * 10 + f) * 8 + i];
                aA = fmaf(w, hA[i], aA);
                aB = fmaf(w, hB[i], aB);
            }
            float dA = sig2(aA) - xnA[f];
            float dB = sig2(aB) - xnB[f];
            if (f & 1) { s1A = fmaf(dA, dA, s1A); s1B = fmaf(dB, dB, s1B); }
            else       { s0A = fmaf(dA, dA, s0A); s0B = fmaf(dB, dB, s0B); }
        }
        float lA = __fsqrt_rn((s0A + s1A) * 0.1f);
        float lB = __fsqrt_rn((s0B + s1B) * 0.1f);
        float tailA = (lA == 0.0f) ? 0.01f : lA;
        float tailB = (lB == 0.0f) ? 0.01f : lB;

        // head normalise -> t (this is an output)
        float hs = ws[1980 + c], hb = ws[1990 + c];
        float tA = fmaf(tailA, hs, hb);
        float tB = fmaf(tailB, hs, hb);

        // accumulate head encoder on the fly (hewT contiguous in c)
        #pragma unroll
        for (int i = 0; i < 8; ++i) {
            float w = ws[2000 + c * 8 + i];
            hhA[i] = fmaf(w, tA, hhA[i]);
            hhB[i] = fmaf(w, tB, hhB[i]);
        }

        // pair up t stores (8B-aligned float2 at even offsets)
        if (c & 1) {
            *reinterpret_cast<float2*>(otA + (c - 1)) = make_float2(tHoldA, tA);
            if (vB) *reinterpret_cast<float2*>(otB + (c - 1)) = make_float2(tHoldB, tB);
        } else {
            tHoldA = tA; tHoldB = tB;
        }
    }

    // ---- head finish ----
    float sA[8], sB[8];
    #pragma unroll
    for (int i = 0; i < 8; ++i) {
        float bb = ws[2080 + i];
        sA[i] = sig2(hhA[i] + bb);
        sB[i] = sig2(hhB[i] + bb);
    }

    float xhA[10], xhB[10];
    #pragma unroll
    for (int c = 0; c < 10; ++c) {
        float a0 = ws[2168 + c];
        float aA = a0, aB = a0;
        #pragma unroll
        for (int i = 0; i < 8; ++i) {
            float w = ws[2088 + c * 8 + i];
            aA = fmaf(w, sA[i], aA);
            aB = fmaf(w, sB[i], aB);
        }
        xhA[c] = sig2(aA);
        xhB[c] = sig2(aB);
    }

    float* poA = out_xhat + (size_t)b0 * 10;
    float* poB = poA + 10;
    #pragma unroll
    for (int j = 0; j < 5; ++j) {
        *reinterpret_cast<float2*>(poA + 2*j) = make_float2(xhA[2*j], xhA[2*j+1]);
        if (vB) *reinterpret_cast<float2*>(poB + 2*j) = make_float2(xhB[2*j], xhB[2*j+1]);
    }
}

extern "C" void kernel_launch(void* const* d_in, const int* in_sizes, int n_in,
                              void* d_out, int out_size, void* d_ws, size_t ws_size,
                              hipStream_t stream) {
    const float* x          = (const float*)d_in[0];
    const float* tail_enc_w = (const float*)d_in[1];
    const float* tail_enc_b = (const float*)d_in[2];
    const float* tail_dec_w = (const float*)d_in[3];
    const float* tail_dec_b = (const float*)d_in[4];
    const float* tail_nmin  = (const float*)d_in[5];
    const float* tail_nmax  = (const float*)d_in[6];
    const float* head_enc_w = (const float*)d_in[7];
    const float* head_enc_b = (const float*)d_in[8];
    const float* head_dec_w = (const float*)d_in[9];
    const float* head_dec_b = (const float*)d_in[10];
    const float* head_nmin  = (const float*)d_in[11];
    const float* head_nmax  = (const float*)d_in[12];

    const int B = in_sizes[0] / 100;

    float* out_xhat = (float*)d_out;             // [B][10], first in tuple
    float* out_t    = out_xhat + (size_t)B * 10; // [B][10], second in tuple
    float* ws       = (float*)d_ws;

    kitsune_prep<<<1, 256, 0, stream>>>(
        tail_enc_w, tail_enc_b, tail_dec_w, tail_dec_b, tail_nmin, tail_nmax,
        head_enc_w, head_enc_b, head_dec_w, head_dec_b, head_nmin, head_nmax, ws);

    const int pairs = (B + 1) / 2;               // thread t does rows 2t, 2t+1
    const int grid  = (pairs + 255) / 256;       // B=524288 -> 1024 blocks
    kitsune_main<<<grid, 256, 0, stream>>>(x, ws, out_xhat, out_t, B);
}

// Round 6
// 92.801 us; speedup vs baseline: 4.1381x; 1.5536x over previous
//
#include <hip/hip_runtime.h>

#define KEPS  1e-16f
#define LOG2E 1.44269504088896340736f

// ---- d_ws float layout (2178 floats) ----
// [0..99]      tsc : 1/(nmax-nmin+eps)              [c][f]
// [100..199]   tbi : -nmin*tsc                      [c][f]
// [200..999]   tew : tail_enc_w * -log2e            [c][i][f]
// [1000..1079] teb : tail_enc_b * -log2e            [c][i]
// [1080..1879] tdw : tail_dec_w * -log2e            [c][f][i]
// [1880..1979] tdb : tail_dec_b * -log2e            [c][f]
// [1980..1989] hsc : head scale                     [c]
// [1990..1999] hbi : -hnmin*hsc                     [c]
// [2000..2079] hewS: head_enc_w * -log2e            [i][c] (original layout)
// [2080..2087] hebS: head_enc_b * -log2e            [i]
// [2088..2167] hdwS: head_dec_w * -log2e            [c][i]
// [2168..2177] hdbS: head_dec_b * -log2e            [c]

__global__ void kitsune_prep(
    const float* __restrict__ tew, const float* __restrict__ teb,
    const float* __restrict__ tdw, const float* __restrict__ tdb,
    const float* __restrict__ tnmin, const float* __restrict__ tnmax,
    const float* __restrict__ hew, const float* __restrict__ heb,
    const float* __restrict__ hdw, const float* __restrict__ hdb,
    const float* __restrict__ hnmin, const float* __restrict__ hnmax,
    float* __restrict__ ws)
{
    const int i = threadIdx.x;  // one block of 256
    for (int k = i; k < 100; k += 256) {
        float s = 1.0f / (tnmax[k] - tnmin[k] + KEPS);
        ws[k]        = s;
        ws[100 + k]  = -tnmin[k] * s;
        ws[1880 + k] = tdb[k] * -LOG2E;
    }
    for (int k = i; k < 800; k += 256) {
        ws[200 + k]  = tew[k] * -LOG2E;
        ws[1080 + k] = tdw[k] * -LOG2E;
    }
    for (int k = i; k < 80; k += 256) {
        ws[1000 + k] = teb[k] * -LOG2E;
        ws[2000 + k] = hew[k] * -LOG2E;   // [i][c], just scaled
        ws[2088 + k] = hdw[k] * -LOG2E;   // [c][i]
    }
    if (i < 10) {
        float s = 1.0f / (hnmax[i] - hnmin[i] + KEPS);
        ws[1980 + i] = s;
        ws[1990 + i] = -hnmin[i] * s;
        ws[2168 + i] = hdb[i] * -LOG2E;
    }
    if (i < 8) ws[2080 + i] = heb[i] * -LOG2E;
}

// sigmoid with -log2e pre-folded into the matmul: sig2(a) = 1/(1+2^a)
__device__ __forceinline__ float sig2(float a) {
    return __builtin_amdgcn_rcpf(1.0f + __builtin_amdgcn_exp2f(a));
}

// Block = 640 threads = 10 waves = 64 rows. Wave w handles cluster w for all
// 64 rows (cluster index wave-uniform -> weight reads are s_loads).
__global__ __launch_bounds__(640, 8) void kitsune_main(
    const float* __restrict__ x,    // [B][100]
    const float* __restrict__ ws,   // prepped params
    float* __restrict__ out_xhat,   // [B][10]
    float* __restrict__ out_t,      // [B][10]
    int B)
{
    __shared__ float xs[64 * 102];  // input tile, row stride 102 (4-way max on b64)
    __shared__ float ts[64 * 11];   // t values, stride 11 (conflict-free)
    __shared__ float hs[64 * 9];    // head hidden (post-sigmoid), stride 9
    __shared__ float os[64 * 11];   // xhat, stride 11

    const int tid  = threadIdx.x;
    const int base = blockIdx.x * 64;
    const int rows = min(64, B - base);

    // ---- phase 1: stage 64 rows, fully coalesced float4 loads ----
    {
        const float4* gx = reinterpret_cast<const float4*>(x + (size_t)base * 100);
        #pragma unroll
        for (int n = 0; n < 3; ++n) {
            int idx = tid + n * 640;          // float4 index in [0, 1600)
            if (idx < rows * 25) {
                float4 v = gx[idx];
                int row = idx / 25;
                int q   = idx - row * 25;
                float* d = xs + row * 102 + q * 4;
                *reinterpret_cast<float2*>(d)     = make_float2(v.x, v.y);
                *reinterpret_cast<float2*>(d + 2) = make_float2(v.z, v.w);
            }
        }
    }
    __syncthreads();

    // ---- phase 2: tail AE; wave w = cluster w, lane = row ----
    {
        const int c = __builtin_amdgcn_readfirstlane(tid >> 6);  // 0..9, uniform
        const int r = tid & 63;

        float xn[10];
        #pragma unroll
        for (int j = 0; j < 5; ++j) {
            float2 v = *reinterpret_cast<const float2*>(xs + r * 102 + c * 10 + 2 * j);
            xn[2 * j]     = v.x;
            xn[2 * j + 1] = v.y;
        }
        #pragma unroll
        for (int f = 0; f < 10; ++f)
            xn[f] = fmaf(xn[f], ws[c * 10 + f], ws[100 + c * 10 + f]);

        float h[8];
        #pragma unroll
        for (int i = 0; i < 8; ++i) {
            float a = ws[1000 + c * 8 + i];
            #pragma unroll
            for (int f = 0; f < 10; ++f)
                a = fmaf(ws[200 + (c * 8 + i) * 10 + f], xn[f], a);
            h[i] = sig2(a);
        }

        float s0 = 0.0f, s1 = 0.0f;
        #pragma unroll
        for (int f = 0; f < 10; ++f) {
            float a = ws[1880 + c * 10 + f];
            #pragma unroll
            for (int i = 0; i < 8; ++i)
                a = fmaf(ws[1080 + (c * 10 + f) * 8 + i], h[i], a);
            float d = sig2(a) - xn[f];
            if (f & 1) s1 = fmaf(d, d, s1);
            else       s0 = fmaf(d, d, s0);
        }
        float l    = __fsqrt_rn((s0 + s1) * 0.1f);
        float tail = (l == 0.0f) ? 0.01f : l;
        ts[r * 11 + c] = fmaf(tail, ws[1980 + c], ws[1990 + c]);
    }
    __syncthreads();

    // ---- phase 3a: head encoder; waves 0..7 = hidden unit i, lane = row ----
    if (tid < 512) {
        const int i = __builtin_amdgcn_readfirstlane(tid >> 6);  // 0..7, uniform
        const int r = tid & 63;
        float a = ws[2080 + i];
        #pragma unroll
        for (int cc = 0; cc < 10; ++cc)
            a = fmaf(ws[2000 + i * 10 + cc], ts[r * 11 + cc], a);
        hs[r * 9 + i] = sig2(a);
    }
    __syncthreads();

    // ---- phase 3b: head decoder; wave w = output c, lane = row ----
    {
        const int c = __builtin_amdgcn_readfirstlane(tid >> 6);  // 0..9, uniform
        const int r = tid & 63;
        float a = ws[2168 + c];
        #pragma unroll
        for (int i = 0; i < 8; ++i)
            a = fmaf(ws[2088 + c * 8 + i], hs[r * 9 + i], a);
        os[r * 11 + c] = sig2(a);
    }
    __syncthreads();

    // ---- phase 4: coalesced float2 stores (threads 0..319 -> t, 320..639 -> xhat) ----
    if (tid < 320) {
        int row = tid / 5, j = tid - row * 5;
        if (row < rows) {
            float2 v = make_float2(ts[row * 11 + 2 * j], ts[row * 11 + 2 * j + 1]);
            *reinterpret_cast<float2*>(out_t + (size_t)(base + row) * 10 + 2 * j) = v;
        }
    } else {
        int q   = tid - 320;
        int row = q / 5, j = q - row * 5;
        if (row < rows) {
            float2 v = make_float2(os[row * 11 + 2 * j], os[row * 11 + 2 * j + 1]);
            *reinterpret_cast<float2*>(out_xhat + (size_t)(base + row) * 10 + 2 * j) = v;
        }
    }
}

extern "C" void kernel_launch(void* const* d_in, const int* in_sizes, int n_in,
                              void* d_out, int out_size, void* d_ws, size_t ws_size,
                              hipStream_t stream) {
    const float* x          = (const float*)d_in[0];
    const float* tail_enc_w = (const float*)d_in[1];
    const float* tail_enc_b = (const float*)d_in[2];
    const float* tail_dec_w = (const float*)d_in[3];
    const float* tail_dec_b = (const float*)d_in[4];
    const float* tail_nmin  = (const float*)d_in[5];
    const float* tail_nmax  = (const float*)d_in[6];
    const float* head_enc_w = (const float*)d_in[7];
    const float* head_enc_b = (const float*)d_in[8];
    const float* head_dec_w = (const float*)d_in[9];
    const float* head_dec_b = (const float*)d_in[10];
    const float* head_nmin  = (const float*)d_in[11];
    const float* head_nmax  = (const float*)d_in[12];

    const int B = in_sizes[0] / 100;

    float* out_xhat = (float*)d_out;             // [B][10], first in tuple
    float* out_t    = out_xhat + (size_t)B * 10; // [B][10], second in tuple
    float* ws       = (float*)d_ws;

    kitsune_prep<<<1, 256, 0, stream>>>(
        tail_enc_w, tail_enc_b, tail_dec_w, tail_dec_b, tail_nmin, tail_nmax,
        head_enc_w, head_enc_b, head_dec_w, head_dec_b, head_nmin, head_nmax, ws);

    const int grid = (B + 63) / 64;              // 64 rows per block
    kitsune_main<<<grid, 640, 0, stream>>>(x, ws, out_xhat, out_t, B);
}

// Round 7
// 92.632 us; speedup vs baseline: 4.1457x; 1.0018x over previous
//
#include <hip/hip_runtime.h>

#define KEPS  1e-16f
#define LOG2E 1.44269504088896340736f

// ---- d_ws float layout (2178 floats) ----
// [0..99]      tsc : 1/(nmax-nmin+eps)              [c][f]
// [100..199]   tbi : -nmin*tsc                      [c][f]
// [200..999]   tew : tail_enc_w * -log2e            [c][i][f]
// [1000..1079] teb : tail_enc_b * -log2e            [c][i]
// [1080..1879] tdw : tail_dec_w * -log2e            [c][f][i]
// [1880..1979] tdb : tail_dec_b * -log2e            [c][f]
// [1980..1989] hsc : head scale                     [c]
// [1990..1999] hbi : -hnmin*hsc                     [c]
// [2000..2079] hewS: head_enc_w * -log2e            [i][c]
// [2080..2087] hebS: head_enc_b * -log2e            [i]
// [2088..2167] hdwS: head_dec_w * -log2e            [c][i]
// [2168..2177] hdbS: head_dec_b * -log2e            [c]

__global__ void kitsune_prep(
    const float* __restrict__ tew, const float* __restrict__ teb,
    const float* __restrict__ tdw, const float* __restrict__ tdb,
    const float* __restrict__ tnmin, const float* __restrict__ tnmax,
    const float* __restrict__ hew, const float* __restrict__ heb,
    const float* __restrict__ hdw, const float* __restrict__ hdb,
    const float* __restrict__ hnmin, const float* __restrict__ hnmax,
    float* __restrict__ ws)
{
    const int i = threadIdx.x;  // one block of 256
    for (int k = i; k < 100; k += 256) {
        float s = 1.0f / (tnmax[k] - tnmin[k] + KEPS);
        ws[k]        = s;
        ws[100 + k]  = -tnmin[k] * s;
        ws[1880 + k] = tdb[k] * -LOG2E;
    }
    for (int k = i; k < 800; k += 256) {
        ws[200 + k]  = tew[k] * -LOG2E;
        ws[1080 + k] = tdw[k] * -LOG2E;
    }
    for (int k = i; k < 80; k += 256) {
        ws[1000 + k] = teb[k] * -LOG2E;
        ws[2000 + k] = hew[k] * -LOG2E;   // [i][c]
        ws[2088 + k] = hdw[k] * -LOG2E;   // [c][i]
    }
    if (i < 10) {
        float s = 1.0f / (hnmax[i] - hnmin[i] + KEPS);
        ws[1980 + i] = s;
        ws[1990 + i] = -hnmin[i] * s;
        ws[2168 + i] = hdb[i] * -LOG2E;
    }
    if (i < 8) ws[2080 + i] = heb[i] * -LOG2E;
}

// sigmoid with -log2e pre-folded into the matmul: sig2(a) = 1/(1+2^a)
__device__ __forceinline__ float sig2(float a) {
    return __builtin_amdgcn_rcpf(1.0f + __builtin_amdgcn_exp2f(a));
}

// Block = 640 threads = 10 waves = 64 rows/tile. Wave w handles cluster w for
// all 64 rows. Blocks grid-stride over tiles with register-prefetch
// double-buffering: tile k+1's global loads fly under tile k's compute.
__global__ __launch_bounds__(640) void kitsune_main(
    const float* __restrict__ x,    // [B][100]
    const float* __restrict__ ws,   // prepped params
    float* __restrict__ out_xhat,   // [B][10]
    float* __restrict__ out_t,      // [B][10]
    int B)
{
    __shared__ float xs[64 * 102];  // input tile, row stride 102 (<=4-way on b64)
    __shared__ float ts[64 * 11];   // t values
    __shared__ float hs[64 * 9];    // head hidden (post-sigmoid)
    __shared__ float os[64 * 11];   // xhat

    const int tid    = threadIdx.x;
    const int g      = (int)gridDim.x;
    const int ntiles = (B + 63) >> 6;

    int tile = (int)blockIdx.x;
    if (tile >= ntiles) return;

    // ---- prefetch first tile into registers (3 float4 per thread max) ----
    float4 pf0, pf1, pf2;
    {
        const int n25 = min(64, B - tile * 64) * 25;
        const float4* gx = reinterpret_cast<const float4*>(x) + (size_t)tile * 1600;
        if (tid < n25)        pf0 = gx[tid];
        if (tid + 640 < n25)  pf1 = gx[tid + 640];
        if (tid + 1280 < n25) pf2 = gx[tid + 1280];
    }

    while (true) {
        const int base = tile * 64;
        const int rows = min(64, B - base);
        const int n25  = rows * 25;

        // ---- commit prefetched tile to LDS ----
        if (tid < n25) {
            int row = tid / 25, q = tid - row * 25;
            float* d = xs + row * 102 + q * 4;
            *reinterpret_cast<float2*>(d)     = make_float2(pf0.x, pf0.y);
            *reinterpret_cast<float2*>(d + 2) = make_float2(pf0.z, pf0.w);
        }
        {
            int i1 = tid + 640;
            if (i1 < n25) {
                int row = i1 / 25, q = i1 - row * 25;
                float* d = xs + row * 102 + q * 4;
                *reinterpret_cast<float2*>(d)     = make_float2(pf1.x, pf1.y);
                *reinterpret_cast<float2*>(d + 2) = make_float2(pf1.z, pf1.w);
            }
            int i2 = tid + 1280;
            if (i2 < n25) {
                int row = i2 / 25, q = i2 - row * 25;
                float* d = xs + row * 102 + q * 4;
                *reinterpret_cast<float2*>(d)     = make_float2(pf2.x, pf2.y);
                *reinterpret_cast<float2*>(d + 2) = make_float2(pf2.z, pf2.w);
            }
        }

        // ---- issue next tile's loads (complete under this tile's compute) ----
        const int next = tile + g;
        if (next < ntiles) {
            const int nn25 = min(64, B - next * 64) * 25;
            const float4* gx = reinterpret_cast<const float4*>(x) + (size_t)next * 1600;
            if (tid < nn25)        pf0 = gx[tid];
            if (tid + 640 < nn25)  pf1 = gx[tid + 640];
            if (tid + 1280 < nn25) pf2 = gx[tid + 1280];
        }
        __syncthreads();

        // ---- phase 2: tail AE; wave w = cluster w, lane = row ----
        {
            const int c = __builtin_amdgcn_readfirstlane(tid >> 6);  // 0..9
            const int r = tid & 63;

            float xn[10];
            #pragma unroll
            for (int j = 0; j < 5; ++j) {
                float2 v = *reinterpret_cast<const float2*>(xs + r * 102 + c * 10 + 2 * j);
                xn[2 * j]     = v.x;
                xn[2 * j + 1] = v.y;
            }
            #pragma unroll
            for (int f = 0; f < 10; ++f)
                xn[f] = fmaf(xn[f], ws[c * 10 + f], ws[100 + c * 10 + f]);

            float h[8];
            #pragma unroll
            for (int i = 0; i < 8; ++i) {
                float a = ws[1000 + c * 8 + i];
                #pragma unroll
                for (int f = 0; f < 10; ++f)
                    a = fmaf(ws[200 + (c * 8 + i) * 10 + f], xn[f], a);
                h[i] = sig2(a);
            }

            float s0 = 0.0f, s1 = 0.0f;
            #pragma unroll
            for (int f = 0; f < 10; ++f) {
                float a = ws[1880 + c * 10 + f];
                #pragma unroll
                for (int i = 0; i < 8; ++i)
                    a = fmaf(ws[1080 + (c * 10 + f) * 8 + i], h[i], a);
                float d = sig2(a) - xn[f];
                if (f & 1) s1 = fmaf(d, d, s1);
                else       s0 = fmaf(d, d, s0);
            }
            float l    = __fsqrt_rn((s0 + s1) * 0.1f);
            float tail = (l == 0.0f) ? 0.01f : l;
            ts[r * 11 + c] = fmaf(tail, ws[1980 + c], ws[1990 + c]);
        }
        __syncthreads();

        // ---- phase 3a: head encoder; waves 0..7 = unit i, lane = row ----
        if (tid < 512) {
            const int i = __builtin_amdgcn_readfirstlane(tid >> 6);  // 0..7
            const int r = tid & 63;
            float a = ws[2080 + i];
            #pragma unroll
            for (int cc = 0; cc < 10; ++cc)
                a = fmaf(ws[2000 + i * 10 + cc], ts[r * 11 + cc], a);
            hs[r * 9 + i] = sig2(a);
        }
        __syncthreads();

        // ---- phase 3b: head decoder; wave w = output c, lane = row ----
        {
            const int c = __builtin_amdgcn_readfirstlane(tid >> 6);  // 0..9
            const int r = tid & 63;
            float a = ws[2168 + c];
            #pragma unroll
            for (int i = 0; i < 8; ++i)
                a = fmaf(ws[2088 + c * 8 + i], hs[r * 9 + i], a);
            os[r * 11 + c] = sig2(a);
        }
        __syncthreads();

        // ---- phase 4: coalesced float2 stores ----
        if (tid < 320) {
            int row = tid / 5, j = tid - row * 5;
            if (row < rows) {
                float2 v = make_float2(ts[row * 11 + 2 * j], ts[row * 11 + 2 * j + 1]);
                *reinterpret_cast<float2*>(out_t + (size_t)(base + row) * 10 + 2 * j) = v;
            }
        } else {
            int q   = tid - 320;
            int row = q / 5, j = q - row * 5;
            if (row < rows) {
                float2 v = make_float2(os[row * 11 + 2 * j], os[row * 11 + 2 * j + 1]);
                *reinterpret_cast<float2*>(out_xhat + (size_t)(base + row) * 10 + 2 * j) = v;
            }
        }
        // NOTE: no end-of-loop barrier needed — next iteration's LDS writes
        // (xs in the commit step, ts/os in phases 2/3b) are all separated from
        // this tile's phase-4 reads by the post-commit __syncthreads().

        if (next >= ntiles) break;
        tile = next;
    }
}

extern "C" void kernel_launch(void* const* d_in, const int* in_sizes, int n_in,
                              void* d_out, int out_size, void* d_ws, size_t ws_size,
                              hipStream_t stream) {
    const float* x          = (const float*)d_in[0];
    const float* tail_enc_w = (const float*)d_in[1];
    const float* tail_enc_b = (const float*)d_in[2];
    const float* tail_dec_w = (const float*)d_in[3];
    const float* tail_dec_b = (const float*)d_in[4];
    const float* tail_nmin  = (const float*)d_in[5];
    const float* tail_nmax  = (const float*)d_in[6];
    const float* head_enc_w = (const float*)d_in[7];
    const float* head_enc_b = (const float*)d_in[8];
    const float* head_dec_w = (const float*)d_in[9];
    const float* head_dec_b = (const float*)d_in[10];
    const float* head_nmin  = (const float*)d_in[11];
    const float* head_nmax  = (const float*)d_in[12];

    const int B = in_sizes[0] / 100;

    float* out_xhat = (float*)d_out;             // [B][10], first in tuple
    float* out_t    = out_xhat + (size_t)B * 10; // [B][10], second in tuple
    float* ws       = (float*)d_ws;

    kitsune_prep<<<1, 256, 0, stream>>>(
        tail_enc_w, tail_enc_b, tail_dec_w, tail_dec_b, tail_nmin, tail_nmax,
        head_enc_w, head_enc_b, head_dec_w, head_dec_b, head_nmin, head_nmax, ws);

    const int ntiles = (B + 63) / 64;
    const int grid   = min(768, ntiles);         // 3 blocks/CU (LDS 34KB, 30 waves)
    kitsune_main<<<grid, 640, 0, stream>>>(x, ws, out_xhat, out_t, B);
}